// Round 1
// baseline (158.814 us; speedup 1.0000x reference)
//
#include <hip/hip_runtime.h>
#include <hip/hip_bf16.h>

#define OUTN 50
constexpr int B_ = 8, C_ = 3, H_ = 1024, W_ = 1024, N_ = 128;

__global__ __launch_bounds__(256) void crop_resize_kernel(
    const float* __restrict__ x,      // [B][C][H][W]
    const float* __restrict__ bbox,   // [N][4] (cx,cy,w,h normalized)
    float* __restrict__ out)          // [N][B][C][OUTN][OUTN]
{
    const int blk = blockIdx.x;           // n * (B*C) + bc
    const int n  = blk / (B_ * C_);
    const int bc = blk % (B_ * C_);

    __shared__ int   sgy0[OUTN], sgy1[OUTN], sgx0[OUTN], sgx1[OUTN];
    __shared__ float swy[OUTN], swx[OUTN];

    const int t = threadIdx.x;

    if (t < 2 * OUTN) {
        // Replicate _xyxy_int in fp32 exactly.
        const float cx = bbox[n * 4 + 0] * (float)W_;
        const float cy = bbox[n * 4 + 1] * (float)H_;
        const float bw = bbox[n * 4 + 2] * (float)W_;
        const float bh = bbox[n * 4 + 3] * (float)H_;

        int x1 = min(max((int)floorf(cx - bw / 2.0f), 0), W_ - 1);
        int y1 = min(max((int)floorf(cy - bh / 2.0f), 0), H_ - 1);
        int x2 = min(max((int)floorf(cx + bw / 2.0f), 0), W_);
        int y2 = min(max((int)floorf(cy + bh / 2.0f), 0), H_);
        x2 = max(x2, x1 + 1);
        y2 = max(y2, y1 + 1);

        const bool isY = (t >= OUTN);
        const int  i   = isY ? (t - OUTN) : t;
        const int  lo  = isY ? y1 : x1;
        const int  hi  = isY ? y2 : x2;

        // _src_coords in fp32: s = clip((i+0.5)*nn/50 - 0.5, 0, nn-1)
        const float nn = (float)(hi - lo);
        float s = ((float)i + 0.5f) * nn / 50.0f - 0.5f;
        s = fminf(fmaxf(s, 0.0f), nn - 1.0f);
        const float i0f = floorf(s);
        const float w1  = s - i0f;
        const int i0 = (int)i0f;
        const int i1 = min(i0 + 1, hi - lo - 1);

        if (isY) { sgy0[i] = lo + i0; sgy1[i] = lo + i1; swy[i] = w1; }
        else     { sgx0[i] = lo + i0; sgx1[i] = lo + i1; swx[i] = w1; }
    }
    __syncthreads();

    const float* __restrict__ xp = x + (size_t)bc * (H_ * W_);
    float* __restrict__ op = out + ((size_t)n * (B_ * C_) + bc) * (OUTN * OUTN);

    for (int idx = t; idx < OUTN * OUTN; idx += blockDim.x) {
        const int oy = idx / OUTN;
        const int ox = idx - oy * OUTN;

        const int gy0 = sgy0[oy], gy1 = sgy1[oy];
        const int gx0 = sgx0[ox], gx1 = sgx1[ox];
        const float wy = swy[oy], wx = swx[ox];

        const float v00 = xp[(size_t)gy0 * W_ + gx0];
        const float v01 = xp[(size_t)gy0 * W_ + gx1];
        const float v10 = xp[(size_t)gy1 * W_ + gx0];
        const float v11 = xp[(size_t)gy1 * W_ + gx1];

        const float top = (1.0f - wx) * v00 + wx * v01;
        const float bot = (1.0f - wx) * v10 + wx * v11;
        op[idx] = (1.0f - wy) * top + wy * bot;
    }
}

extern "C" void kernel_launch(void* const* d_in, const int* in_sizes, int n_in,
                              void* d_out, int out_size, void* d_ws, size_t ws_size,
                              hipStream_t stream) {
    const float* x    = (const float*)d_in[0];
    const float* bbox = (const float*)d_in[1];
    float* out = (float*)d_out;

    const int nblocks = N_ * B_ * C_;  // 3072
    crop_resize_kernel<<<nblocks, 256, 0, stream>>>(x, bbox, out);
}

// Round 2
// 157.578 us; speedup vs baseline: 1.0078x; 1.0078x over previous
//
#include <hip/hip_runtime.h>
#include <hip/hip_bf16.h>

#define OUTN 50
constexpr int B_ = 8, C_ = 3, H_ = 1024, W_ = 1024, N_ = 128;
constexpr int PLANES = B_ * C_;          // 24
constexpr int PIX    = OUTN * OUTN;      // 2500
constexpr int TPB    = 256;
constexpr int ITER   = (PIX + TPB - 1) / TPB;  // 10

__global__ __launch_bounds__(TPB) void crop_resize_kernel(
    const float* __restrict__ x,      // [B][C][H][W]
    const float* __restrict__ bbox,   // [N][4]
    float* __restrict__ out)          // [N][B][C][OUTN][OUTN]
{
    // XCD-aware decode: bc is a function of blockIdx%8 so each XCD's L2
    // only sees 3 of the 24 source planes.
    const int blk = blockIdx.x;            // 0..3071
    const int xcd = blk & 7;
    const int r   = blk >> 3;              // 0..383
    const int bc  = xcd * 3 + (r % 3);     // 0..23
    const int n   = r / 3;                 // 0..127

    // Packed per-axis tables:
    //  sy[i] = { gy0*W, gy1*W, bits(wy), 0 }
    //  sx[i] = { a = min(gx0, W-2), sel = gx0-a, bits(wx), 0 }
    __shared__ int4 sy[OUTN], sx[OUTN];

    const int t = threadIdx.x;

    if (t < 2 * OUTN) {
        const float4 bb = reinterpret_cast<const float4*>(bbox)[n];
        const float cx = bb.x * (float)W_;
        const float cy = bb.y * (float)H_;
        const float bw = bb.z * (float)W_;
        const float bh = bb.w * (float)H_;

        int x1 = min(max((int)floorf(cx - bw / 2.0f), 0), W_ - 1);
        int y1 = min(max((int)floorf(cy - bh / 2.0f), 0), H_ - 1);
        int x2 = min(max((int)floorf(cx + bw / 2.0f), 0), W_);
        int y2 = min(max((int)floorf(cy + bh / 2.0f), 0), H_);
        x2 = max(x2, x1 + 1);
        y2 = max(y2, y1 + 1);

        const bool isY = (t >= OUTN);
        const int  i   = isY ? (t - OUTN) : t;
        const int  lo  = isY ? y1 : x1;
        const int  hi  = isY ? y2 : x2;

        const float nn = (float)(hi - lo);
        float s = ((float)i + 0.5f) * nn / 50.0f - 0.5f;
        s = fminf(fmaxf(s, 0.0f), nn - 1.0f);
        const float i0f = floorf(s);
        const float w1  = s - i0f;          // == 0 exactly whenever i1 clamps
        const int   i0  = (int)i0f;
        const int   i1  = min(i0 + 1, hi - lo - 1);

        if (isY) {
            sy[i] = make_int4((lo + i0) * W_, (lo + i1) * W_,
                              __float_as_int(w1), 0);
        } else {
            const int g0  = lo + i0;
            const int a   = min(g0, W_ - 2);   // float2 at a is always in-row
            sx[i] = make_int4(a, g0 - a, __float_as_int(w1), 0);
        }
    }
    __syncthreads();

    const float* __restrict__ xp = x + (size_t)bc * (H_ * W_);
    float* __restrict__ op = out + ((size_t)n * PLANES + bc) * PIX;

#pragma unroll
    for (int k = 0; k < ITER; ++k) {
        const int idx_raw = t + k * TPB;
        const int idx = (idx_raw < PIX) ? idx_raw : (PIX - 1);  // safe addr
        const int oy = idx / OUTN;
        const int ox = idx - oy * OUTN;

        const int4 yv = sy[oy];
        const int4 xv = sx[ox];
        const float wy = __int_as_float(yv.z);
        const float wx = __int_as_float(xv.z);

        // Two taps per row via one 8-byte load. When gx0 == W-1 (sel==1),
        // v00 is .y; the bogus v01 is multiplied by wx == 0 exactly.
        // When gx1 clamped interior (w1==0), bogus .y also weighted by 0.
        const float2 t0 = *reinterpret_cast<const float2*>(xp + yv.x + xv.x);
        const float2 t1 = *reinterpret_cast<const float2*>(xp + yv.y + xv.x);

        const float v00 = xv.y ? t0.y : t0.x;
        const float v01 = t0.y;
        const float v10 = xv.y ? t1.y : t1.x;
        const float v11 = t1.y;

        const float top = (1.0f - wx) * v00 + wx * v01;
        const float bot = (1.0f - wx) * v10 + wx * v11;
        const float val = (1.0f - wy) * top + wy * bot;

        if (idx_raw < PIX) {
            __builtin_nontemporal_store(val, &op[idx_raw]);
        }
    }
}

extern "C" void kernel_launch(void* const* d_in, const int* in_sizes, int n_in,
                              void* d_out, int out_size, void* d_ws, size_t ws_size,
                              hipStream_t stream) {
    const float* x    = (const float*)d_in[0];
    const float* bbox = (const float*)d_in[1];
    float* out = (float*)d_out;

    crop_resize_kernel<<<N_ * PLANES, TPB, 0, stream>>>(x, bbox, out);
}

// Round 3
// 155.856 us; speedup vs baseline: 1.0190x; 1.0110x over previous
//
#include <hip/hip_runtime.h>
#include <hip/hip_bf16.h>

#define OUTN 50
constexpr int B_ = 8, C_ = 3, H_ = 1024, W_ = 1024, N_ = 128;
constexpr int PLANES = B_ * C_;          // 24
constexpr int PIX    = OUTN * OUTN;      // 2500
constexpr int TPB    = 256;
constexpr int ITER   = (PIX + TPB - 1) / TPB;  // 10

__global__ __launch_bounds__(TPB) void crop_resize_kernel(
    const float* __restrict__ x,      // [B][C][H][W]
    const float* __restrict__ bbox,   // [N][4]
    float* __restrict__ out)          // [N][B][C][OUTN][OUTN]
{
    // XCD-temporal blocking: blk&7 selects the XCD (HW round-robin);
    // within an XCD the 384 blocks are PLANE-MAJOR (128 consecutive blocks
    // = one plane, all boxes). Concurrent working set per XCD ≈ one plane's
    // touched region (~2 MB) < 4 MB L2, so each source line is fetched once
    // per XCD and reused across all resident boxes.
    const int blk = blockIdx.x;            // 0..3071
    const int xcd = blk & 7;
    const int r   = blk >> 3;              // 0..383
    const int bc  = xcd * 3 + (r >> 7);    // plane: 3 per XCD, changes SLOWEST
    const int n   = r & 127;               // box index, changes fastest

    // Packed per-axis tables:
    //  sy[i] = { gy0*W, gy1*W, bits(wy), 0 }
    //  sx[i] = { a = min(gx0, W-2), sel = gx0-a, bits(wx), 0 }
    __shared__ int4 sy[OUTN], sx[OUTN];

    const int t = threadIdx.x;

    if (t < 2 * OUTN) {
        const float4 bb = reinterpret_cast<const float4*>(bbox)[n];
        const float cx = bb.x * (float)W_;
        const float cy = bb.y * (float)H_;
        const float bw = bb.z * (float)W_;
        const float bh = bb.w * (float)H_;

        int x1 = min(max((int)floorf(cx - bw / 2.0f), 0), W_ - 1);
        int y1 = min(max((int)floorf(cy - bh / 2.0f), 0), H_ - 1);
        int x2 = min(max((int)floorf(cx + bw / 2.0f), 0), W_);
        int y2 = min(max((int)floorf(cy + bh / 2.0f), 0), H_);
        x2 = max(x2, x1 + 1);
        y2 = max(y2, y1 + 1);

        const bool isY = (t >= OUTN);
        const int  i   = isY ? (t - OUTN) : t;
        const int  lo  = isY ? y1 : x1;
        const int  hi  = isY ? y2 : x2;

        const float nn = (float)(hi - lo);
        float s = ((float)i + 0.5f) * nn / 50.0f - 0.5f;
        s = fminf(fmaxf(s, 0.0f), nn - 1.0f);
        const float i0f = floorf(s);
        const float w1  = s - i0f;          // == 0 exactly whenever i1 clamps
        const int   i0  = (int)i0f;
        const int   i1  = min(i0 + 1, hi - lo - 1);

        if (isY) {
            sy[i] = make_int4((lo + i0) * W_, (lo + i1) * W_,
                              __float_as_int(w1), 0);
        } else {
            const int g0  = lo + i0;
            const int a   = min(g0, W_ - 2);   // float2 at a is always in-row
            sx[i] = make_int4(a, g0 - a, __float_as_int(w1), 0);
        }
    }
    __syncthreads();

    const float* __restrict__ xp = x + (size_t)bc * (H_ * W_);
    float* __restrict__ op = out + ((size_t)n * PLANES + bc) * PIX;

#pragma unroll
    for (int k = 0; k < ITER; ++k) {
        const int idx_raw = t + k * TPB;
        const int idx = (idx_raw < PIX) ? idx_raw : (PIX - 1);  // safe addr
        const int oy = idx / OUTN;
        const int ox = idx - oy * OUTN;

        const int4 yv = sy[oy];
        const int4 xv = sx[ox];
        const float wy = __int_as_float(yv.z);
        const float wx = __int_as_float(xv.z);

        // Two taps per row via one 8-byte load. When gx0 == W-1 (sel==1),
        // v00 is .y; the bogus v01 is multiplied by wx == 0 exactly.
        const float2 t0 = *reinterpret_cast<const float2*>(xp + yv.x + xv.x);
        const float2 t1 = *reinterpret_cast<const float2*>(xp + yv.y + xv.x);

        const float v00 = xv.y ? t0.y : t0.x;
        const float v01 = t0.y;
        const float v10 = xv.y ? t1.y : t1.x;
        const float v11 = t1.y;

        const float top = (1.0f - wx) * v00 + wx * v01;
        const float bot = (1.0f - wx) * v10 + wx * v11;
        const float val = (1.0f - wy) * top + wy * bot;

        if (idx_raw < PIX) {
            __builtin_nontemporal_store(val, &op[idx_raw]);
        }
    }
}

extern "C" void kernel_launch(void* const* d_in, const int* in_sizes, int n_in,
                              void* d_out, int out_size, void* d_ws, size_t ws_size,
                              hipStream_t stream) {
    const float* x    = (const float*)d_in[0];
    const float* bbox = (const float*)d_in[1];
    float* out = (float*)d_out;

    crop_resize_kernel<<<N_ * PLANES, TPB, 0, stream>>>(x, bbox, out);
}